// Round 7
// baseline (161.223 us; speedup 1.0000x reference)
//
#include <hip/hip_runtime.h>

#define SDIM 8192
#define RAD  256     // WINDOW_SIZE/2
#define GTOK 64
#define KSEL 8
#define CAP  768
#define THRESH 2.2f  // P(N(0,1)>2.2)=1.39% -> ~114 candidates/row; [8,768] is >30 sigma safe

// ---- kernel A: issue row loads -> write band/global mask row (independent of
// loads, overlaps their latency) -> threshold filter -> wave-0 exact top-8 ->
// lanes t<8 fix up random mask cells; t0 writes count. No global state needed.
__global__ __launch_bounds__(256) void pass1_kernel(const float* __restrict__ scores,
                                                    int* __restrict__ rand_idx,
                                                    int* __restrict__ counts,
                                                    float* __restrict__ cnt_out,
                                                    float* __restrict__ mask_out) {
    __shared__ float cand_v[CAP];
    __shared__ int   cand_i[CAP];
    __shared__ int   top8[KSEL];
    __shared__ int   cnt;
    const int row = blockIdx.x;
    const int t   = threadIdx.x;
    if (t == 0) cnt = 0;
    __syncthreads();

    // issue all row loads first (8 outstanding float4/thread, coalesced)
    const float4* rowp = reinterpret_cast<const float4*>(scores + (size_t)row * SDIM);
    float4 d[8];
#pragma unroll
    for (int k = 0; k < 8; k++) d[k] = rowp[t + k * 256];

    // band/global mask row write — independent of the loads; fills their latency
    int wlo = row - RAD; if (wlo < 0) wlo = 0;
    int whi = row + RAD; if (whi > SDIM - 1) whi = SDIM - 1;
    const unsigned wspan = (unsigned)(whi - wlo);
    const bool full = row < GTOK;
    float4* mrow = reinterpret_cast<float4*>(mask_out + (size_t)row * SDIM);
#pragma unroll
    for (int k = 0; k < 8; k++) {
        int f4 = t + k * 256;
        int jb = f4 * 4;
        float4 o; float* op = &o.x;
#pragma unroll
        for (int e = 0; e < 4; e++) {
            int j = jb + e;
            op[e] = (full || (j < GTOK) || ((unsigned)(j - wlo) <= wspan)) ? 1.0f : 0.0f;
        }
        mrow[f4] = o;
    }

    // threshold filter into LDS candidates (consumes d, which then dies)
#pragma unroll
    for (int k = 0; k < 8; k++) {
        int jb = (t + k * 256) * 4;
        if (d[k].x > THRESH) { int p = atomicAdd(&cnt, 1); if (p < CAP) { cand_v[p] = d[k].x; cand_i[p] = jb;     } }
        if (d[k].y > THRESH) { int p = atomicAdd(&cnt, 1); if (p < CAP) { cand_v[p] = d[k].y; cand_i[p] = jb + 1; } }
        if (d[k].z > THRESH) { int p = atomicAdd(&cnt, 1); if (p < CAP) { cand_v[p] = d[k].z; cand_i[p] = jb + 2; } }
        if (d[k].w > THRESH) { int p = atomicAdd(&cnt, 1); if (p < CAP) { cand_v[p] = d[k].w; cand_i[p] = jb + 3; } }
    }
    __syncthreads();

    const int n = cnt;
    const bool bad = (n < KSEL || n > CAP);   // block-uniform

    if (!bad) {
        // wave-0 exact top-8 of candidate set (argmax rounds, ties -> lower idx)
        if (t < 64) {
            for (int round = 0; round < KSEL; round++) {
                float bv = -INFINITY; int bi = 0x7fffffff;
                for (int c = t; c < n; c += 64) {
                    float val = cand_v[c]; int id = cand_i[c];
                    if (val > bv || (val == bv && id < bi)) { bv = val; bi = id; }
                }
#pragma unroll
                for (int s = 32; s > 0; s >>= 1) {
                    float ov = __shfl_down(bv, s);
                    int   oi = __shfl_down(bi, s);
                    if (ov > bv || (ov == bv && oi < bi)) { bv = ov; bi = oi; }
                }
                bi = __shfl(bi, 0);
                for (int c = t; c < n; c += 64) if (cand_i[c] == bi) cand_v[c] = -INFINITY;
                if (t == 0) top8[round] = bi;
            }
        }
    } else {
        // exact inline fallback (data-independence guard; never fires for the
        // fixed input). Reloads the L2-hot row so d[] stays dead here.
        for (int round = 0; round < KSEL; round++) {
            float bv = -INFINITY; int bi = 0x7fffffff;
            for (int k = 0; k < 8; k++) {
                int f4 = t + k * 256;
                float4 dd = rowp[f4];
                float vals[4] = {dd.x, dd.y, dd.z, dd.w};
                int jb = f4 * 4;
                for (int e = 0; e < 4; e++) {
                    int j = jb + e;
                    bool used = false;
                    for (int q = 0; q < round; q++) used = used || (top8[q] == j);
                    if (!used && vals[e] > bv) { bv = vals[e]; bi = j; }  // ascending j -> ties to lowest
                }
            }
            cand_v[t] = bv; cand_i[t] = bi;
            __syncthreads();
            if (t < 64) {
                for (int c = t + 64; c < 256; c += 64) {
                    float vv = cand_v[c]; int ii = cand_i[c];
                    if (vv > bv || (vv == bv && ii < bi)) { bv = vv; bi = ii; }
                }
#pragma unroll
                for (int s = 32; s > 0; s >>= 1) {
                    float ov = __shfl_down(bv, s);
                    int   oi = __shfl_down(bi, s);
                    if (ov > bv || (ov == bv && oi < bi)) { bv = ov; bi = oi; }
                }
                if (t == 0) top8[round] = bi;
            }
            __syncthreads();
        }
    }
    __syncthreads();

    // epilogue: lanes t<8 fix up random mask cells + rand_idx; t0 writes count
    if (t < KSEL) {
        int r = top8[t];
        rand_idx[row * KSEL + t] = r;
        mask_out[(size_t)row * SDIM + r] = 1.0f;   // idempotent if already 1
    }
    if (t == 0) {
        int c;
        if (full) c = SDIM;
        else {
            c = (whi - wlo + 1) + (wlo < GTOK ? wlo : GTOK);
#pragma unroll
            for (int q = 0; q < KSEL; q++) {
                int r = top8[q];
                if (r >= GTOK && (r < wlo || r > whi)) c++;
            }
        }
        counts[row] = c;
        cnt_out[row] = (float)c;
    }
}

// ---- kernel B: per-row offset by direct 64-lane sum of counts[0..row) (L2-hot),
// then offsets/cols/sparsity
__global__ __launch_bounds__(256) void col_kernel(const int* __restrict__ rand_idx,
                                                  const int* __restrict__ counts,
                                                  float* __restrict__ off_out,
                                                  float* __restrict__ col_out,
                                                  float* __restrict__ sp_out) {
    __shared__ int cs[256];
    __shared__ int s_off;
    const int row = blockIdx.x;
    const int t   = threadIdx.x;

    // offset = sum(counts[0..row)) — strided, coalesced, L2-resident (32 KB)
    if (t < 64) {
        int acc = 0;
        for (int i = t; i < row; i += 64) acc += counts[i];
#pragma unroll
        for (int s = 32; s > 0; s >>= 1) acc += __shfl_down(acc, s);
        if (t == 0) s_off = acc;
    }
    __syncthreads();
    const int offset = s_off;

    int r[KSEL];
#pragma unroll
    for (int q = 0; q < KSEL; q++) r[q] = rand_idx[row * KSEL + q];
    const bool full = row < GTOK;
    int wlo = row - RAD; if (wlo < 0) wlo = 0;
    int whi = row + RAD; if (whi > SDIM - 1) whi = SDIM - 1;

    const int jb = t * 32;
    unsigned int bm;
    if (full || jb + 31 < GTOK) {
        bm = ~0u;
    } else {
        bm = 0u;
        int lo = wlo > jb ? wlo : jb;
        int hi = whi < jb + 31 ? whi : jb + 31;
        if (lo <= hi) {
            int a = lo - jb, z = hi - jb;
            unsigned hiM = (z == 31) ? ~0u : ((1u << (z + 1)) - 1u);
            unsigned loM = (1u << a) - 1u;
            bm = hiM & ~loM;
        }
#pragma unroll
        for (int q = 0; q < KSEL; q++)
            if ((r[q] >> 5) == t) bm |= 1u << (r[q] & 31);
    }
    cs[t] = __popc(bm);
    __syncthreads();
    for (int d = 1; d < 256; d <<= 1) {
        int add = (t >= d) ? cs[t - d] : 0;
        __syncthreads();
        cs[t] += add;
        __syncthreads();
    }
    int pos = offset + ((t == 0) ? 0 : cs[t - 1]);
    for (int e = 0; e < 32; e++) {
        if ((bm >> e) & 1u) col_out[pos++] = (float)(jb + e);
    }

    if (t == 0) {
        off_out[row] = (float)offset;
        if (row == SDIM - 1) {
            int total = offset + counts[row];
            off_out[SDIM] = (float)total;
            sp_out[0] = (float)total / 67108864.0f;   // < 2^24 -> exact
        }
    }
}

extern "C" void kernel_launch(void* const* d_in, const int* in_sizes, int n_in,
                              void* d_out, int out_size, void* d_ws, size_t ws_size,
                              hipStream_t stream) {
    const float* scores = (const float*)d_in[1];   // rand_scores [S,S] f32

    float* out_f    = (float*)d_out;
    float* mask_out = out_f;                                   // S*S
    float* off_out  = out_f + (size_t)SDIM * SDIM;             // S+1
    float* col_out  = off_out + (SDIM + 1);                    // TC
    const long long TC = (long long)out_size
                       - ((long long)SDIM * SDIM + (SDIM + 1) + SDIM + 1);
    float* cnt_out = col_out + TC;                             // S
    float* sp_out  = cnt_out + SDIM;                           // 1

    int* rand_idx = (int*)d_ws;                  // S*K ints
    int* counts   = rand_idx + SDIM * KSEL;      // S ints

    pass1_kernel<<<SDIM, 256, 0, stream>>>(scores, rand_idx, counts, cnt_out, mask_out);
    col_kernel<<<SDIM, 256, 0, stream>>>(rand_idx, counts, off_out, col_out, sp_out);
}

// Round 9
// 134.828 us; speedup vs baseline: 1.1958x; 1.1958x over previous
//
#include <hip/hip_runtime.h>

#define SDIM 8192
#define RAD  256     // WINDOW_SIZE/2
#define GTOK 64
#define KSEL 8
#define CAP  768
#define THRESH 2.2f  // P(N(0,1)>2.2)=1.39% -> ~114 candidates/row; [8,768] is >30 sigma safe

typedef float f32x4 __attribute__((ext_vector_type(4)));   // native vec for NT stores

// ---- kernel A: issue row loads -> NT-write band/global mask row (independent
// of loads) -> ballot-compacted threshold filter (no per-element dependent
// atomics) -> wave-0 exact top-8 -> t<8 fix up random mask cells; t0 count.
__global__ __launch_bounds__(256) void pass1_kernel(const float* __restrict__ scores,
                                                    int* __restrict__ rand_idx,
                                                    int* __restrict__ counts,
                                                    float* __restrict__ cnt_out,
                                                    float* __restrict__ mask_out) {
    __shared__ float cand_v[CAP];
    __shared__ int   cand_i[CAP];
    __shared__ int   top8[KSEL];
    __shared__ int   cnt;
    const int row  = blockIdx.x;
    const int t    = threadIdx.x;
    const int lane = t & 63;
    if (t == 0) cnt = 0;
    __syncthreads();

    // issue all row loads first (8 outstanding float4/thread, coalesced)
    const f32x4* rowp = reinterpret_cast<const f32x4*>(scores + (size_t)row * SDIM);
    f32x4 d[8];
#pragma unroll
    for (int k = 0; k < 8; k++) d[k] = rowp[t + k * 256];

    // band/global mask row (independent of loads; fills their latency).
    // Non-temporal: mask is write-once, never re-read -> don't evict scores.
    int wlo = row - RAD; if (wlo < 0) wlo = 0;
    int whi = row + RAD; if (whi > SDIM - 1) whi = SDIM - 1;
    const unsigned wspan = (unsigned)(whi - wlo);
    const bool full = row < GTOK;
    f32x4* mrow = reinterpret_cast<f32x4*>(mask_out + (size_t)row * SDIM);
#pragma unroll
    for (int k = 0; k < 8; k++) {
        int f4 = t + k * 256;
        int jb = f4 * 4;
        f32x4 o;
#pragma unroll
        for (int e = 0; e < 4; e++) {
            int j = jb + e;
            o[e] = (full || (j < GTOK) || ((unsigned)(j - wlo) <= wspan)) ? 1.0f : 0.0f;
        }
        __builtin_nontemporal_store(o, mrow + f4);
    }

    // ballot-compacted threshold filter: one LDS atomic per wave per hit-group
#pragma unroll
    for (int k = 0; k < 8; k++) {
        int jb = (t + k * 256) * 4;
#pragma unroll
        for (int e = 0; e < 4; e++) {
            float val = d[k][e];
            bool pred = val > THRESH;
            unsigned long long m = __ballot(pred);
            if (m != 0ull) {                       // wave-uniform
                int base = 0;
                if (lane == 0) base = atomicAdd(&cnt, __popcll(m));
                base = __shfl(base, 0);
                int off = __builtin_amdgcn_mbcnt_lo((unsigned)m, 0);
                off = __builtin_amdgcn_mbcnt_hi((unsigned)(m >> 32), off);
                int p = base + off;
                if (pred && p < CAP) { cand_v[p] = val; cand_i[p] = jb + e; }
            }
        }
    }
    __syncthreads();

    const int n = cnt;
    const bool bad = (n < KSEL || n > CAP);   // block-uniform

    if (!bad) {
        // wave-0 exact top-8 of candidate set (argmax rounds, ties -> lower idx)
        if (t < 64) {
            for (int round = 0; round < KSEL; round++) {
                float bv = -INFINITY; int bi = 0x7fffffff;
                for (int c = t; c < n; c += 64) {
                    float val = cand_v[c]; int id = cand_i[c];
                    if (val > bv || (val == bv && id < bi)) { bv = val; bi = id; }
                }
#pragma unroll
                for (int s = 32; s > 0; s >>= 1) {
                    float ov = __shfl_down(bv, s);
                    int   oi = __shfl_down(bi, s);
                    if (ov > bv || (ov == bv && oi < bi)) { bv = ov; bi = oi; }
                }
                bi = __shfl(bi, 0);
                for (int c = t; c < n; c += 64) if (cand_i[c] == bi) cand_v[c] = -INFINITY;
                if (t == 0) top8[round] = bi;
            }
        }
    } else {
        // exact inline fallback (data-independence guard; never fires for the
        // fixed input). Reloads the L2/L3-hot row.
        for (int round = 0; round < KSEL; round++) {
            float bv = -INFINITY; int bi = 0x7fffffff;
            for (int k = 0; k < 8; k++) {
                int f4 = t + k * 256;
                f32x4 dd = rowp[f4];
                int jb = f4 * 4;
                for (int e = 0; e < 4; e++) {
                    int j = jb + e;
                    bool used = false;
                    for (int q = 0; q < round; q++) used = used || (top8[q] == j);
                    if (!used && dd[e] > bv) { bv = dd[e]; bi = j; }  // ascending j -> ties to lowest
                }
            }
            cand_v[t] = bv; cand_i[t] = bi;
            __syncthreads();
            if (t < 64) {
                for (int c = t + 64; c < 256; c += 64) {
                    float vv = cand_v[c]; int ii = cand_i[c];
                    if (vv > bv || (vv == bv && ii < bi)) { bv = vv; bi = ii; }
                }
#pragma unroll
                for (int s = 32; s > 0; s >>= 1) {
                    float ov = __shfl_down(bv, s);
                    int   oi = __shfl_down(bi, s);
                    if (ov > bv || (ov == bv && oi < bi)) { bv = ov; bi = oi; }
                }
                if (t == 0) top8[round] = bi;
            }
            __syncthreads();
        }
    }
    __syncthreads();

    // epilogue: t<8 fix up random mask cells + rand_idx; t0 writes count
    if (t < KSEL) {
        int r = top8[t];
        rand_idx[row * KSEL + t] = r;
        mask_out[(size_t)row * SDIM + r] = 1.0f;   // idempotent if already 1
    }
    if (t == 0) {
        int c;
        if (full) c = SDIM;
        else {
            c = (whi - wlo + 1) + (wlo < GTOK ? wlo : GTOK);
#pragma unroll
            for (int q = 0; q < KSEL; q++) {
                int r = top8[q];
                if (r >= GTOK && (r < wlo || r > whi)) c++;
            }
        }
        counts[row] = c;
        cnt_out[row] = (float)c;
    }
}

// ---- kernel B: 64-row group partial sums (plain stores; no atomics/memset)
__global__ __launch_bounds__(64) void partial_kernel(const int* __restrict__ counts,
                                                     int* __restrict__ partials) {
    int acc = counts[blockIdx.x * 64 + threadIdx.x];
#pragma unroll
    for (int s = 32; s > 0; s >>= 1) acc += __shfl_down(acc, s);
    if (threadIdx.x == 0) partials[blockIdx.x] = acc;
}

// ---- kernel C: per-row offset from partials+counts (L2-hot), then LDS-staged
// coalesced col_indices + offsets + sparsity
__global__ __launch_bounds__(256) void col_kernel(const int* __restrict__ rand_idx,
                                                  const int* __restrict__ counts,
                                                  const int* __restrict__ partials,
                                                  float* __restrict__ off_out,
                                                  float* __restrict__ col_out,
                                                  float* __restrict__ sp_out) {
    __shared__ float stage[SDIM];   // 32 KB, worst case global row
    __shared__ int cs[256];
    __shared__ int s_off;
    const int row = blockIdx.x;
    const int t   = threadIdx.x;

    // offset = sum(partials[0..g)) + sum(counts[g*64..row))
    if (t < 64) {
        const int g = row >> 6;
        int acc = 0;
        for (int h = t; h < g; h += 64) acc += partials[h];
        for (int i = (g << 6) + t; i < row; i += 64) acc += counts[i];
#pragma unroll
        for (int s = 32; s > 0; s >>= 1) acc += __shfl_down(acc, s);
        if (t == 0) s_off = acc;
    }

    int r[KSEL];
#pragma unroll
    for (int q = 0; q < KSEL; q++) r[q] = rand_idx[row * KSEL + q];
    const bool full = row < GTOK;
    int wlo = row - RAD; if (wlo < 0) wlo = 0;
    int whi = row + RAD; if (whi > SDIM - 1) whi = SDIM - 1;

    const int jb = t * 32;
    unsigned int bm;
    if (full || jb + 31 < GTOK) {
        bm = ~0u;
    } else {
        bm = 0u;
        int lo = wlo > jb ? wlo : jb;
        int hi = whi < jb + 31 ? whi : jb + 31;
        if (lo <= hi) {
            int a = lo - jb, z = hi - jb;
            unsigned hiM = (z == 31) ? ~0u : ((1u << (z + 1)) - 1u);
            unsigned loM = (1u << a) - 1u;
            bm = hiM & ~loM;
        }
#pragma unroll
        for (int q = 0; q < KSEL; q++)
            if ((r[q] >> 5) == t) bm |= 1u << (r[q] & 31);
    }
    cs[t] = __popc(bm);
    __syncthreads();
    for (int d = 1; d < 256; d <<= 1) {
        int add = (t >= d) ? cs[t - d] : 0;
        __syncthreads();
        cs[t] += add;
        __syncthreads();
    }

    // stage this row's column list in LDS (ascending j), then coalesced copy
    int pos = (t == 0) ? 0 : cs[t - 1];
    for (int e = 0; e < 32; e++) {
        if ((bm >> e) & 1u) stage[pos++] = (float)(jb + e);
    }
    __syncthreads();
    const int offset = s_off;
    const int total  = cs[255];
    for (int i = t; i < total; i += 256)
        __builtin_nontemporal_store(stage[i], col_out + offset + i);

    if (t == 0) {
        off_out[row] = (float)offset;
        if (row == SDIM - 1) {
            int tot = offset + counts[row];
            off_out[SDIM] = (float)tot;
            sp_out[0] = (float)tot / 67108864.0f;   // < 2^24 -> exact
        }
    }
}

extern "C" void kernel_launch(void* const* d_in, const int* in_sizes, int n_in,
                              void* d_out, int out_size, void* d_ws, size_t ws_size,
                              hipStream_t stream) {
    const float* scores = (const float*)d_in[1];   // rand_scores [S,S] f32

    float* out_f    = (float*)d_out;
    float* mask_out = out_f;                                   // S*S
    float* off_out  = out_f + (size_t)SDIM * SDIM;             // S+1
    float* col_out  = off_out + (SDIM + 1);                    // TC
    const long long TC = (long long)out_size
                       - ((long long)SDIM * SDIM + (SDIM + 1) + SDIM + 1);
    float* cnt_out = col_out + TC;                             // S
    float* sp_out  = cnt_out + SDIM;                           // 1

    int* rand_idx = (int*)d_ws;                  // S*K ints
    int* counts   = rand_idx + SDIM * KSEL;      // S ints
    int* partials = counts + SDIM;               // 128 ints

    pass1_kernel<<<SDIM, 256, 0, stream>>>(scores, rand_idx, counts, cnt_out, mask_out);
    partial_kernel<<<SDIM / 64, 64, 0, stream>>>(counts, partials);
    col_kernel<<<SDIM, 256, 0, stream>>>(rand_idx, counts, partials,
                                         off_out, col_out, sp_out);
}

// Round 10
// 128.534 us; speedup vs baseline: 1.2543x; 1.0490x over previous
//
#include <hip/hip_runtime.h>

#define SDIM 8192
#define RAD  256     // WINDOW_SIZE/2
#define GTOK 64
#define KSEL 8
#define CAP  768
#define SLOTS (CAP / 64)
#define THRESH 2.2f  // P(N(0,1)>2.2)=1.39% -> ~114 candidates/row; [8,768] is >30 sigma safe

typedef float f32x4 __attribute__((ext_vector_type(4)));   // native vec for NT stores

// ---- kernel A: issue row loads -> NT-write band/global mask row -> ballot-
// compacted threshold filter -> wave-0 REGISTER-resident top-8 (one LDS read,
// 8 reg-argmax rounds w/ shfl_xor butterfly) -> t<8 mask fixups; t0 count.
__global__ __launch_bounds__(256) void pass1_kernel(const float* __restrict__ scores,
                                                    int* __restrict__ rand_idx,
                                                    int* __restrict__ counts,
                                                    float* __restrict__ cnt_out,
                                                    float* __restrict__ mask_out) {
    __shared__ float cand_v[CAP];
    __shared__ int   cand_i[CAP];
    __shared__ int   top8[KSEL];
    __shared__ int   cnt;
    const int row  = blockIdx.x;
    const int t    = threadIdx.x;
    const int lane = t & 63;
    if (t == 0) cnt = 0;
    __syncthreads();

    // issue all row loads first (8 outstanding float4/thread, coalesced)
    const f32x4* rowp = reinterpret_cast<const f32x4*>(scores + (size_t)row * SDIM);
    f32x4 d[8];
#pragma unroll
    for (int k = 0; k < 8; k++) d[k] = rowp[t + k * 256];

    // band/global mask row (independent of loads; fills their latency).
    // Non-temporal: write-once, never re-read -> keep scores resident in L2/L3.
    int wlo = row - RAD; if (wlo < 0) wlo = 0;
    int whi = row + RAD; if (whi > SDIM - 1) whi = SDIM - 1;
    const unsigned wspan = (unsigned)(whi - wlo);
    const bool full = row < GTOK;
    f32x4* mrow = reinterpret_cast<f32x4*>(mask_out + (size_t)row * SDIM);
#pragma unroll
    for (int k = 0; k < 8; k++) {
        int f4 = t + k * 256;
        int jb = f4 * 4;
        f32x4 o;
#pragma unroll
        for (int e = 0; e < 4; e++) {
            int j = jb + e;
            o[e] = (full || (j < GTOK) || ((unsigned)(j - wlo) <= wspan)) ? 1.0f : 0.0f;
        }
        __builtin_nontemporal_store(o, mrow + f4);
    }

    // ballot-compacted threshold filter: one LDS atomic per wave per hit-group
#pragma unroll
    for (int k = 0; k < 8; k++) {
        int jb = (t + k * 256) * 4;
#pragma unroll
        for (int e = 0; e < 4; e++) {
            float val = d[k][e];
            bool pred = val > THRESH;
            unsigned long long m = __ballot(pred);
            if (m != 0ull) {                       // wave-uniform
                int base = 0;
                if (lane == 0) base = atomicAdd(&cnt, __popcll(m));
                base = __shfl(base, 0);
                int off = __builtin_amdgcn_mbcnt_lo((unsigned)m, 0);
                off = __builtin_amdgcn_mbcnt_hi((unsigned)(m >> 32), off);
                int p = base + off;
                if (pred && p < CAP) { cand_v[p] = val; cand_i[p] = jb + e; }
            }
        }
    }
    __syncthreads();

    const int n = cnt;
    const bool bad = (n < KSEL || n > CAP);   // block-uniform

    if (!bad) {
        // wave-0: load candidates to regs ONCE, then 8 pure-register argmax
        // rounds (ties -> lower index); shfl_xor butterfly = no broadcast step
        if (t < 64) {
            float sv[SLOTS]; int si[SLOTS];
#pragma unroll
            for (int s = 0; s < SLOTS; s++) {
                int c = t + s * 64;
                if (c < n) { sv[s] = cand_v[c]; si[s] = cand_i[c]; }
                else       { sv[s] = -INFINITY; si[s] = 0x7fffffff; }
            }
            for (int round = 0; round < KSEL; round++) {
                float bv = -INFINITY; int bi = 0x7fffffff;
#pragma unroll
                for (int s = 0; s < SLOTS; s++) {
                    if (sv[s] > bv || (sv[s] == bv && si[s] < bi)) { bv = sv[s]; bi = si[s]; }
                }
#pragma unroll
                for (int s = 1; s < 64; s <<= 1) {
                    float ov = __shfl_xor(bv, s);
                    int   oi = __shfl_xor(bi, s);
                    if (ov > bv || (ov == bv && oi < bi)) { bv = ov; bi = oi; }
                }
                if (t == 0) top8[round] = bi;
#pragma unroll
                for (int s = 0; s < SLOTS; s++)
                    if (si[s] == bi) sv[s] = -INFINITY;
            }
        }
    } else {
        // exact inline fallback (data-independence guard; never fires for the
        // fixed input). Reloads the L2/L3-hot row.
        for (int round = 0; round < KSEL; round++) {
            float bv = -INFINITY; int bi = 0x7fffffff;
            for (int k = 0; k < 8; k++) {
                int f4 = t + k * 256;
                f32x4 dd = rowp[f4];
                int jb = f4 * 4;
                for (int e = 0; e < 4; e++) {
                    int j = jb + e;
                    bool used = false;
                    for (int q = 0; q < round; q++) used = used || (top8[q] == j);
                    if (!used && dd[e] > bv) { bv = dd[e]; bi = j; }  // ascending j -> ties to lowest
                }
            }
            cand_v[t] = bv; cand_i[t] = bi;
            __syncthreads();
            if (t < 64) {
                for (int c = t + 64; c < 256; c += 64) {
                    float vv = cand_v[c]; int ii = cand_i[c];
                    if (vv > bv || (vv == bv && ii < bi)) { bv = vv; bi = ii; }
                }
#pragma unroll
                for (int s = 32; s > 0; s >>= 1) {
                    float ov = __shfl_down(bv, s);
                    int   oi = __shfl_down(bi, s);
                    if (ov > bv || (ov == bv && oi < bi)) { bv = ov; bi = oi; }
                }
                if (t == 0) top8[round] = bi;
            }
            __syncthreads();
        }
    }
    __syncthreads();

    // epilogue: t<8 fix up random mask cells + rand_idx; t0 writes count
    if (t < KSEL) {
        int r = top8[t];
        rand_idx[row * KSEL + t] = r;
        mask_out[(size_t)row * SDIM + r] = 1.0f;   // idempotent if already 1
    }
    if (t == 0) {
        int c;
        if (full) c = SDIM;
        else {
            c = (whi - wlo + 1) + (wlo < GTOK ? wlo : GTOK);
#pragma unroll
            for (int q = 0; q < KSEL; q++) {
                int r = top8[q];
                if (r >= GTOK && (r < wlo || r > whi)) c++;
            }
        }
        counts[row] = c;
        cnt_out[row] = (float)c;
    }
}

// ---- kernel B: 64-row group partial sums (plain stores; no atomics/memset)
__global__ __launch_bounds__(64) void partial_kernel(const int* __restrict__ counts,
                                                     int* __restrict__ partials) {
    int acc = counts[blockIdx.x * 64 + threadIdx.x];
#pragma unroll
    for (int s = 32; s > 0; s >>= 1) acc += __shfl_down(acc, s);
    if (threadIdx.x == 0) partials[blockIdx.x] = acc;
}

// ---- kernel C: per-row offset from partials+counts (L2-hot); ANALYTIC prefix
// positions (no block scan, no scan barriers); LDS-staged coalesced NT writes
__global__ __launch_bounds__(256) void col_kernel(const int* __restrict__ rand_idx,
                                                  const int* __restrict__ counts,
                                                  const int* __restrict__ partials,
                                                  float* __restrict__ off_out,
                                                  float* __restrict__ col_out,
                                                  float* __restrict__ sp_out) {
    __shared__ float stage[SDIM];   // 32 KB, worst case global row
    __shared__ int s_off, s_total;
    const int row = blockIdx.x;
    const int t   = threadIdx.x;

    // offset = sum(partials[0..g)) + sum(counts[g*64..row))
    if (t < 64) {
        const int g = row >> 6;
        int acc = 0;
        for (int h = t; h < g; h += 64) acc += partials[h];
        for (int i = (g << 6) + t; i < row; i += 64) acc += counts[i];
#pragma unroll
        for (int s = 32; s > 0; s >>= 1) acc += __shfl_down(acc, s);
        if (t == 0) s_off = acc;
    }

    int r[KSEL];
#pragma unroll
    for (int q = 0; q < KSEL; q++) r[q] = rand_idx[row * KSEL + q];
    const bool full = row < GTOK;
    int wlo = row - RAD; if (wlo < 0) wlo = 0;
    int whi = row + RAD; if (whi > SDIM - 1) whi = SDIM - 1;

    const int jb = t * 32;
    unsigned int bm;
    int pos;
    if (full) {
        bm = ~0u;
        pos = jb;
    } else if (jb + 31 < GTOK) {
        bm = ~0u;
        pos = jb;                       // cols 0..63 region: identity prefix
    } else {
        bm = 0u;
        int lo = wlo > jb ? wlo : jb;
        int hi = whi < jb + 31 ? whi : jb + 31;
        if (lo <= hi) {
            int a = lo - jb, z = hi - jb;
            unsigned hiM = (z == 31) ? ~0u : ((1u << (z + 1)) - 1u);
            unsigned loM = (1u << a) - 1u;
            bm = hiM & ~loM;
        }
#pragma unroll
        for (int q = 0; q < KSEL; q++)
            if ((r[q] >> 5) == t) bm |= 1u << (r[q] & 31);
        // analytic exclusive prefix at column jb
        int glob   = jb < GTOK ? jb : GTOK;
        int bandlo = wlo > GTOK ? wlo : GTOK;
        int bandhi = jb < whi + 1 ? jb : whi + 1;
        int band   = bandhi - bandlo; if (band < 0) band = 0;
        int extr = 0;
#pragma unroll
        for (int q = 0; q < KSEL; q++) {
            int rq = r[q];
            bool ex = (rq >= GTOK) && (rq < wlo || rq > whi);
            extr += (ex && rq < jb) ? 1 : 0;
        }
        pos = glob + band + extr;
    }
    if (t == 255) s_total = pos + __popc(bm);

    // stage this row's column list (ascending j) at exact analytic positions
    for (int e = 0; e < 32; e++) {
        if ((bm >> e) & 1u) stage[pos++] = (float)(jb + e);
    }
    __syncthreads();
    const int offset = s_off;
    const int total  = s_total;
    for (int i = t; i < total; i += 256)
        __builtin_nontemporal_store(stage[i], col_out + offset + i);

    if (t == 0) {
        off_out[row] = (float)offset;
        if (row == SDIM - 1) {
            int tot = offset + total;
            off_out[SDIM] = (float)tot;
            sp_out[0] = (float)tot / 67108864.0f;   // < 2^24 -> exact
        }
    }
}

extern "C" void kernel_launch(void* const* d_in, const int* in_sizes, int n_in,
                              void* d_out, int out_size, void* d_ws, size_t ws_size,
                              hipStream_t stream) {
    const float* scores = (const float*)d_in[1];   // rand_scores [S,S] f32

    float* out_f    = (float*)d_out;
    float* mask_out = out_f;                                   // S*S
    float* off_out  = out_f + (size_t)SDIM * SDIM;             // S+1
    float* col_out  = off_out + (SDIM + 1);                    // TC
    const long long TC = (long long)out_size
                       - ((long long)SDIM * SDIM + (SDIM + 1) + SDIM + 1);
    float* cnt_out = col_out + TC;                             // S
    float* sp_out  = cnt_out + SDIM;                           // 1

    int* rand_idx = (int*)d_ws;                  // S*K ints
    int* counts   = rand_idx + SDIM * KSEL;      // S ints
    int* partials = counts + SDIM;               // 128 ints

    pass1_kernel<<<SDIM, 256, 0, stream>>>(scores, rand_idx, counts, cnt_out, mask_out);
    partial_kernel<<<SDIM / 64, 64, 0, stream>>>(counts, partials);
    col_kernel<<<SDIM, 256, 0, stream>>>(rand_idx, counts, partials,
                                         off_out, col_out, sp_out);
}